// Round 7
// baseline (184.659 us; speedup 1.0000x reference)
//
#include <hip/hip_runtime.h>

// 5x5 normalized box blur, REFLECT_101, fp32, NCHW 32x3x512x512.
// Dense lane mapping (R6): lane owns cols 4*lane (half 0) and 256+4*lane
// (half 1); every store is a fully-dense 1KB wave transaction.
// NEW: zero shuffles. Horizontal halo comes from overlapping loads:
// per half-row, two dwordx4 at c-2 and c+2 cover cols c-2..c+5 lane-locally.
// (Multi-dword global loads need only dword alignment on CDNA; the 8B-offset
// bases are fine. Adjacent lanes overlap 2x in L1 -- HBM unaffected.)
// Edge lanes clamp their load base inside the row and patch via cndmask.
// Vertical 5-tap = running sum, RPT=4 rows/thread, 3 rows (A/B/C) rolling
// => 12 dwordx4 loads in flight per wave. No DS ops at all.
// Block: 4 waves -> 16-row full-width strip. Grid: 32 x 96 = 3072 blocks.

#define WID 512
#define HEI 512
#define RPT 4                 // output rows per thread
#define STRIP (4 * RPT)       // 16 rows per block (4 waves)

typedef float v4f __attribute__((ext_vector_type(4)));

struct Row { v4f a0, a1, b0, b1; };   // a: cols cA-2..cA+5, b: cols cB-2..cB+5

__global__ __launch_bounds__(256) void smooth_box5_kernel(
    const float* __restrict__ in, float* __restrict__ out)
{
    const int tid  = threadIdx.x;
    const int lane = tid & 63;
    const int wv   = tid >> 6;              // wave id 0..3
    const int r0   = blockIdx.x * STRIP + wv * RPT;
    const long long plane = blockIdx.y;

    const float* __restrict__ ip = in  + plane * (long long)(HEI * WID);
    float*       __restrict__ op = out + plane * (long long)(HEI * WID);

    const int cA = lane * 4;                // half 0: cols 0..255
    const int cB = 256 + lane * 4;          // half 1: cols 256..511
    const bool l0  = (lane == 0);
    const bool l63 = (lane == 63);

    // Per-lane load bases (clamped at image edges; patched in hsum).
    const int offA0 = l0  ? 0       : cA - 2;   // cols cA-2..cA+1 (lane0: 0..3)
    const int offA1 = cA + 2;                   // cols cA+2..cA+5
    const int offB0 = cB - 2;                   // cols cB-2..cB+1
    const int offB1 = l63 ? cB      : cB + 2;   // cols cB+2..cB+5 (lane63: 508..511)

    auto loadrow = [&](int gy, Row& R) {
        gy = (gy < 0) ? -gy : ((gy >= HEI) ? (2 * HEI - 2 - gy) : gy);
        const float* row = ip + gy * WID;
        R.a0 = *reinterpret_cast<const v4f*>(row + offA0);
        R.a1 = *reinterpret_cast<const v4f*>(row + offA1);
        R.b0 = *reinterpret_cast<const v4f*>(row + offB0);
        R.b1 = *reinterpret_cast<const v4f*>(row + offB1);
    };

    // Horizontal 5-tap sums (unnormalized), h[0..3]=cols cA..cA+3,
    // h[4..7]=cols cB..cB+3. Pure VALU; edge lanes patched via selects.
    auto hsum = [&](const Row& R, float h[8]) {
        // half 0: e0[k] = col cA-2+k. lane0 loaded a0 at col0 = {c0,c1,c2,c3};
        // needs {refl(-2)=c2, refl(-1)=c1, c0,c1,c2,c3,c4,c5}.
        float e0[8] = {
            l0 ? R.a0.z : R.a0.x,
            R.a0.y,
            l0 ? R.a0.x : R.a0.z,
            l0 ? R.a0.y : R.a0.w,
            l0 ? R.a0.z : R.a1.x,
            l0 ? R.a0.w : R.a1.y,
            R.a1.z,
            R.a1.w };
        // half 1: e1[k] = col cB-2+k. lane63 loaded b1 at 508 = {508..511};
        // needs tail {c510,c511, refl(512)=c510, refl(513)=c509}.
        float e1[8] = {
            R.b0.x, R.b0.y, R.b0.z, R.b0.w,
            l63 ? R.b1.z : R.b1.x,
            l63 ? R.b1.w : R.b1.y,
            R.b1.z,
            l63 ? R.b1.y : R.b1.w };
        float t0[6], t1[6];
        #pragma unroll
        for (int j = 0; j < 6; ++j) { t0[j] = e0[j] + e0[j + 1]; t1[j] = e1[j] + e1[j + 1]; }
        #pragma unroll
        for (int j = 0; j < 4; ++j) {
            h[j]     = t0[j] + t0[j + 2] + e0[j + 4];
            h[4 + j] = t1[j] + t1[j + 2] + e1[j + 4];
        }
    };

    auto storerow = [&](float* p, const float vsum[8]) {
        v4f o0 = { vsum[0]*0.04f, vsum[1]*0.04f, vsum[2]*0.04f, vsum[3]*0.04f };
        v4f o1 = { vsum[4]*0.04f, vsum[5]*0.04f, vsum[6]*0.04f, vsum[7]*0.04f };
        *reinterpret_cast<v4f*>(p + cA) = o0;          // dense 1KB
        *reinterpret_cast<v4f*>(p + cB) = o1;          // dense 1KB
    };

    Row A, B, C;
    float h[4][8];     // rows r0-2 .. r0+1 (the only rows ever subtracted)
    float hn[8];       // scratch for rows r0+2 .. r0+5
    float vs[8];

    // Prologue: keep 3 row-loads (12 dwordx4) in flight at all times.
    loadrow(r0 - 2, A);
    loadrow(r0 - 1, B);
    loadrow(r0,     C);
    hsum(A, h[0]); loadrow(r0 + 1, A);
    hsum(B, h[1]); loadrow(r0 + 2, B);
    hsum(C, h[2]); loadrow(r0 + 3, C);
    hsum(A, h[3]); loadrow(r0 + 4, A);

    #pragma unroll
    for (int j = 0; j < 8; ++j)
        vs[j] = h[0][j] + h[1][j] + h[2][j] + h[3][j];

    float* orow = op + (long long)r0 * WID;

    // k = 0: window rows r0-2..r0+2 ; new row r0+2 is in B
    hsum(B, hn); loadrow(r0 + 5, B);
    #pragma unroll
    for (int j = 0; j < 8; ++j) vs[j] += hn[j];
    storerow(orow, vs);
    #pragma unroll
    for (int j = 0; j < 8; ++j) vs[j] -= h[0][j];
    orow += WID;

    // k = 1: new row r0+3 in C
    hsum(C, hn);
    #pragma unroll
    for (int j = 0; j < 8; ++j) vs[j] += hn[j];
    storerow(orow, vs);
    #pragma unroll
    for (int j = 0; j < 8; ++j) vs[j] -= h[1][j];
    orow += WID;

    // k = 2: new row r0+4 in A
    hsum(A, hn);
    #pragma unroll
    for (int j = 0; j < 8; ++j) vs[j] += hn[j];
    storerow(orow, vs);
    #pragma unroll
    for (int j = 0; j < 8; ++j) vs[j] -= h[2][j];
    orow += WID;

    // k = 3: new row r0+5 in B
    hsum(B, hn);
    #pragma unroll
    for (int j = 0; j < 8; ++j) vs[j] += hn[j];
    storerow(orow, vs);
}

extern "C" void kernel_launch(void* const* d_in, const int* in_sizes, int n_in,
                              void* d_out, int out_size, void* d_ws, size_t ws_size,
                              hipStream_t stream) {
    const float* img = (const float*)d_in[0];
    float* out = (float*)d_out;
    // Shapes fixed by the reference: (32, 3, 512, 512), w = 5.
    const int B = 32, C = 3;
    dim3 grid(HEI / STRIP, B * C);   // 32 x 96 = 3072 blocks
    dim3 block(256);
    smooth_box5_kernel<<<grid, block, 0, stream>>>(img, out);
}

// Round 9
// 176.987 us; speedup vs baseline: 1.0433x; 1.0433x over previous
//
#include <hip/hip_runtime.h>

// 5x5 normalized box blur, REFLECT_101, fp32, NCHW 32x3x512x512.
// Block = 16-row full-width strip of one (b,c) plane.
// Stage 20 input rows (2KB each) into LDS via global_load_lds (width=16,
// fire-and-forget DMA): 40 x 1KB chunks, 10 per wave, all in flight at
// once -> 40KB outstanding per block, 4 blocks/CU (160KB LDS) => MLP no
// longer limited by compiler vmcnt waits on VGPR-staged loads (R0-R7 were
// all pinned at ~3 TB/s = ~1 outstanding load/wave).
// One barrier, then pure-LDS compute: dense aligned ds_read_b128/b64,
// horizontal 5-tap lane-local, vertical 5-tap running sum (4 rows/thread).
// Dense store mapping (R6): lane owns cols 4*lane and 256+4*lane.
// Grid: 32 x 96 = 3072 blocks, 256 threads.

#define WID 512
#define HEI 512
#define RPT 4                  // output rows per thread
#define STRIP 16               // output rows per block (4 waves)
#define NROW (STRIP + 4)       // staged input rows (incl. vertical halo)

typedef float v4f __attribute__((ext_vector_type(4)));
typedef float v2f __attribute__((ext_vector_type(2)));

__global__ __launch_bounds__(256) void smooth_box5_kernel(
    const float* __restrict__ in, float* __restrict__ out)
{
    __shared__ float s[NROW][WID];          // 20 x 2KB = 40 KB

    const int tid  = threadIdx.x;
    const int lane = tid & 63;
    const int wv   = tid >> 6;              // wave id 0..3
    const int tileY = blockIdx.x * STRIP;
    const long long plane = blockIdx.y;

    const float* __restrict__ ip = in  + plane * (long long)(HEI * WID);
    float*       __restrict__ op = out + plane * (long long)(HEI * WID);

    const bool l0  = (lane == 0);
    const bool l63 = (lane == 63);

    // ---- stage: 40 chunks (row j, half h) -> s[j][h*256 + 4*lane], 10/wave ----
    #pragma unroll
    for (int k = 0; k < 10; ++k) {
        const int q    = wv + 4 * k;        // 0..39
        const int j    = q >> 1;
        const int half = q & 1;
        int gy = tileY - 2 + j;             // REFLECT_101 row
        gy = (gy < 0) ? -gy : ((gy >= HEI) ? (2 * HEI - 2 - gy) : gy);
        const float* gp = ip + (long long)gy * WID + half * 256 + lane * 4;
        float* lp = &s[j][half * 256];      // HW adds lane*16B
        __builtin_amdgcn_global_load_lds(
            (const __attribute__((address_space(1))) void*)gp,
            (__attribute__((address_space(3))) void*)lp,
            16, 0, 0);
    }
    __syncthreads();                        // drains vmcnt(0): all 40 DMAs done

    // ---- horizontal 5-tap from LDS (lane-local, aligned reads) ----
    // h[0..3] = cols 4*lane .. 4*lane+3 ; h[4..7] = cols 256+4*lane ..
    auto hsum = [&](int j, float h[8]) {
        const float* row = &s[j][0];
        const int cA = 4 * lane;
        v4f mA = *reinterpret_cast<const v4f*>(&row[cA]);
        v2f LA = *reinterpret_cast<const v2f*>(&row[l0 ? 0 : cA - 2]);
        v2f RA = *reinterpret_cast<const v2f*>(&row[cA + 4]);          // <=257: ok
        v4f mB = *reinterpret_cast<const v4f*>(&row[256 + cA]);
        v2f LB = *reinterpret_cast<const v2f*>(&row[254 + cA]);        // >=254: ok
        v2f RB = *reinterpret_cast<const v2f*>(&row[l63 ? 506 : 260 + cA]);
        // e0[k] = col cA-2+k ; image-left reflect for lane0 (cols -2,-1 -> 2,1)
        float e0[8] = { l0 ? mA.z : LA.x, l0 ? mA.y : LA.y,
                        mA.x, mA.y, mA.z, mA.w, RA.x, RA.y };
        // e1[k] = col 256+cA-2+k ; image-right reflect for lane63 (512,513 -> 510,509)
        float e1[8] = { LB.x, LB.y, mB.x, mB.y, mB.z, mB.w,
                        l63 ? mB.z : RB.x, l63 ? mB.y : RB.y };
        float t0[6], t1[6];
        #pragma unroll
        for (int m = 0; m < 6; ++m) { t0[m] = e0[m] + e0[m + 1]; t1[m] = e1[m] + e1[m + 1]; }
        #pragma unroll
        for (int m = 0; m < 4; ++m) {
            h[m]     = t0[m] + t0[m + 2] + e0[m + 4];
            h[4 + m] = t1[m] + t1[m + 2] + e1[m + 4];
        }
    };

    auto storerow = [&](float* p, const float vsum[8]) {
        v4f o0 = { vsum[0]*0.04f, vsum[1]*0.04f, vsum[2]*0.04f, vsum[3]*0.04f };
        v4f o1 = { vsum[4]*0.04f, vsum[5]*0.04f, vsum[6]*0.04f, vsum[7]*0.04f };
        *reinterpret_cast<v4f*>(p + 4 * lane)       = o0;   // dense 1KB
        *reinterpret_cast<v4f*>(p + 256 + 4 * lane) = o1;   // dense 1KB
    };

    // ---- vertical 5-tap: wave w -> output rows tileY+4w .. +3 ----
    // Output row tileY+4w+i needs LDS rows jb+i .. jb+i+4, jb = 4*wv.
    const int jb = 4 * wv;
    float h[4][8], hn[8], vs[8];

    hsum(jb + 0, h[0]);
    hsum(jb + 1, h[1]);
    hsum(jb + 2, h[2]);
    hsum(jb + 3, h[3]);
    #pragma unroll
    for (int m = 0; m < 8; ++m)
        vs[m] = h[0][m] + h[1][m] + h[2][m] + h[3][m];

    float* orow = op + (long long)(tileY + 4 * wv) * WID;

    #pragma unroll
    for (int k = 0; k < RPT; ++k) {
        hsum(jb + 4 + k, hn);
        #pragma unroll
        for (int m = 0; m < 8; ++m) vs[m] += hn[m];
        storerow(orow, vs);
        #pragma unroll
        for (int m = 0; m < 8; ++m) vs[m] -= h[k][m];   // static index (unrolled)
        orow += WID;
    }
}

extern "C" void kernel_launch(void* const* d_in, const int* in_sizes, int n_in,
                              void* d_out, int out_size, void* d_ws, size_t ws_size,
                              hipStream_t stream) {
    const float* img = (const float*)d_in[0];
    float* out = (float*)d_out;
    // Shapes fixed by the reference: (32, 3, 512, 512), w = 5.
    const int B = 32, C = 3;
    dim3 grid(HEI / STRIP, B * C);   // 32 x 96 = 3072 blocks
    dim3 block(256);
    smooth_box5_kernel<<<grid, block, 0, stream>>>(img, out);
}